// Round 1
// baseline (162.573 us; speedup 1.0000x reference)
//
#include <hip/hip_runtime.h>
#include <math.h>

// B=2, N=512, D=64, DH=64
#define NN 512
#define DH 64

// ---------- generic 3-way projection: out_k = in @ W_k + b_k, rows of 64 ----------
__global__ __launch_bounds__(64) void proj3_kernel(
    const float* __restrict__ in,
    const float* __restrict__ W0, const float* __restrict__ b0,
    const float* __restrict__ W1, const float* __restrict__ b1,
    const float* __restrict__ W2, const float* __restrict__ b2,
    float* __restrict__ o0, float* __restrict__ o1, float* __restrict__ o2)
{
    const int row = blockIdx.x;
    const int d = threadIdx.x;
    __shared__ float xr[64];
    xr[d] = in[row * 64 + d];
    __syncthreads();
    float a0 = b0[d], a1 = b1[d], a2 = b2[d];
#pragma unroll
    for (int k = 0; k < 64; ++k) {
        const float xv = xr[k];
        a0 = fmaf(xv, W0[k * 64 + d], a0);
        a1 = fmaf(xv, W1[k * 64 + d], a1);
        a2 = fmaf(xv, W2[k * 64 + d], a2);
    }
    o0[row * 64 + d] = a0;
    o1[row * 64 + d] = a1;
    o2[row * 64 + d] = a2;
}

// ---------- node-to-node self attention: x_hat = softmax(QK^T/8) @ V ----------
__global__ __launch_bounds__(256) void selfattn_kernel(
    const float* __restrict__ Q, const float* __restrict__ K,
    const float* __restrict__ V, float* __restrict__ xhat)
{
    const int row = blockIdx.x;            // b*512 + n
    const int b = row >> 9;
    const int t = threadIdx.x;
    __shared__ float qr[64];
    __shared__ float p[512];
    __shared__ float red[256];
    if (t < 64) qr[t] = Q[row * 64 + t];
    __syncthreads();
    for (int m = t; m < NN; m += 256) {
        const float4* kr = (const float4*)(K + (b * NN + m) * 64);
        float s = 0.f;
#pragma unroll
        for (int k2 = 0; k2 < 16; ++k2) {
            float4 w = kr[k2];
            const float* q4 = qr + k2 * 4;
            s += q4[0] * w.x + q4[1] * w.y + q4[2] * w.z + q4[3] * w.w;
        }
        p[m] = s * 0.125f;
    }
    __syncthreads();
    // max reduce
    float v0 = p[t], v1 = p[t + 256];
    red[t] = fmaxf(v0, v1);
    __syncthreads();
    for (int o = 128; o; o >>= 1) { if (t < o) red[t] = fmaxf(red[t], red[t + o]); __syncthreads(); }
    const float mx = red[0];
    __syncthreads();
    const float e0 = expf(v0 - mx), e1 = expf(v1 - mx);
    p[t] = e0; p[t + 256] = e1;
    red[t] = e0 + e1;
    __syncthreads();
    for (int o = 128; o; o >>= 1) { if (t < o) red[t] += red[t + o]; __syncthreads(); }
    const float inv = 1.f / red[0];
    __syncthreads();
    // x_hat: d = t&63, quarter q = t>>6
    const int d = t & 63, q = t >> 6;
    float acc = 0.f;
    const int m0 = q * 128;
    for (int m = m0; m < m0 + 128; ++m)
        acc = fmaf(p[m], V[(b * NN + m) * 64 + d], acc);
    red[t] = acc;
    __syncthreads();
    if (t < 64)
        xhat[row * 64 + t] = (red[t] + red[t + 64] + red[t + 128] + red[t + 192]) * inv;
}

// ---------- derived small tensors: P = Wqe@Kn, q0 = bqe.Kn/8, VnWke, VnWve ----------
__global__ __launch_bounds__(64) void derive_kernel(
    const float* __restrict__ Kn, const float* __restrict__ Vn,
    const float* __restrict__ Wqe, const float* __restrict__ bqe,
    const float* __restrict__ Wke, const float* __restrict__ Wve,
    float* __restrict__ P, float* __restrict__ q0,
    float* __restrict__ VnWke, float* __restrict__ VnWve)
{
    const int row = blockIdx.x;
    const int d = threadIdx.x;
    __shared__ float knr[64], vnr[64], red[64];
    knr[d] = Kn[row * 64 + d];
    vnr[d] = Vn[row * 64 + d];
    __syncthreads();
    float pd = 0.f, ake = 0.f, ave = 0.f;
#pragma unroll
    for (int k = 0; k < 64; ++k) {
        pd  = fmaf(Wqe[d * 64 + k], knr[k], pd);    // row d of Wqe . Kn
        ake = fmaf(vnr[k], Wke[k * 64 + d], ake);
        ave = fmaf(vnr[k], Wve[k * 64 + d], ave);
    }
    P[row * 64 + d] = pd;
    VnWke[row * 64 + d] = ake;
    VnWve[row * 64 + d] = ave;
    red[d] = bqe[d] * knr[d];
    __syncthreads();
    for (int o = 32; o; o >>= 1) { if (d < o) red[d] += red[d + o]; __syncthreads(); }
    if (d == 0) q0[row] = red[0] * 0.125f;
}

// ---------- the big streaming pass over e: Ai + e_new ----------
__global__ __launch_bounds__(256) void edge_kernel(
    const float* __restrict__ e, const float* __restrict__ P,
    const float* __restrict__ q0, const float* __restrict__ Vn,
    float* __restrict__ e_new, float* __restrict__ AiBuf)
{
    const int t = threadIdx.x;
    const int r = t >> 4;          // row within block (16 rows/block)
    const int k = t & 15;          // float4 lane within row
    const int rowidx = blockIdx.x * 16 + r;   // (b*512+i)*512 + j
    const int j  = rowidx & 511;
    const int bi = rowidx >> 9;    // b*512 + i
    const int b  = bi >> 9;
    const int bj = b * NN + j;

    const float4 ev = ((const float4*)e)[rowidx * 16 + k];
    const float4 pj = ((const float4*)P)[bj * 16 + k];
    const float4 pi = ((const float4*)P)[bi * 16 + k];
    float s = ev.x * (pj.x - pi.x) + ev.y * (pj.y - pi.y)
            + ev.z * (pj.z - pi.z) + ev.w * (pj.w - pi.w);
    s += __shfl_xor(s, 1);
    s += __shfl_xor(s, 2);
    s += __shfl_xor(s, 4);
    s += __shfl_xor(s, 8);
    s = s * 0.125f + q0[bj] - q0[bi];
    const float ai = 1.f / (1.f + expf(-s));

    const float4 vi = ((const float4*)Vn)[bi * 16 + k];
    const float4 vj = ((const float4*)Vn)[bj * 16 + k];
    float4 en;
    en.x = fmaf(ai, vj.x - vi.x, vi.x);
    en.y = fmaf(ai, vj.y - vi.y, vi.y);
    en.z = fmaf(ai, vj.z - vi.z, vi.z);
    en.w = fmaf(ai, vj.w - vi.w, vi.w);
    ((float4*)e_new)[rowidx * 16 + k] = en;
    if (k == 0) AiBuf[rowidx] = ai;
}

// ---------- edge-to-node: x_new, using only Ai + small tensors ----------
__global__ __launch_bounds__(256) void node_kernel(
    const float* __restrict__ Qn, const float* __restrict__ VnWke,
    const float* __restrict__ VnWve, const float* __restrict__ bve,
    const float* __restrict__ AiBuf, float* __restrict__ x_new)
{
    const int row = blockIdx.x;    // b*512 + i
    const int b = row >> 9, i = row & 511;
    const int t = threadIdx.x;
    __shared__ float qn[64];
    __shared__ float u[512];
    __shared__ float as[512];
    __shared__ float c[512];
    __shared__ float red[256];
    if (t < 64) qn[t] = Qn[row * 64 + t];
    __syncthreads();
    for (int j = t; j < NN; j += 256) {
        const float4* wr = (const float4*)(VnWke + (b * NN + j) * 64);
        float s = 0.f;
#pragma unroll
        for (int k2 = 0; k2 < 16; ++k2) {
            float4 w = wr[k2];
            const float* q4 = qn + k2 * 4;
            s += q4[0] * w.x + q4[1] * w.y + q4[2] * w.z + q4[3] * w.w;
        }
        u[j] = s * 0.125f;
        as[j] = AiBuf[row * NN + j];
    }
    __syncthreads();
    const float uii = u[i];
    const float v0 = as[t] * (u[t] - uii);
    const float v1 = as[t + 256] * (u[t + 256] - uii);
    // softmax over the 512 v's (constants cancel)
    red[t] = fmaxf(v0, v1);
    __syncthreads();
    for (int o = 128; o; o >>= 1) { if (t < o) red[t] = fmaxf(red[t], red[t + o]); __syncthreads(); }
    const float mx = red[0];
    __syncthreads();
    const float e0 = expf(v0 - mx), e1 = expf(v1 - mx);
    red[t] = e0 + e1;
    __syncthreads();
    for (int o = 128; o; o >>= 1) { if (t < o) red[t] += red[t + o]; __syncthreads(); }
    const float inv = 1.f / red[0];
    __syncthreads();
    const float c0 = e0 * inv * as[t], c1 = e1 * inv * as[t + 256];
    c[t] = c0; c[t + 256] = c1;
    red[t] = c0 + c1;
    __syncthreads();
    for (int o = 128; o; o >>= 1) { if (t < o) red[t] += red[t + o]; __syncthreads(); }
    const float g = red[0];
    __syncthreads();
    const int d = t & 63, q = t >> 6;
    float acc = 0.f;
    const int j0 = q * 128;
    for (int j = j0; j < j0 + 128; ++j)
        acc = fmaf(c[j], VnWve[(b * NN + j) * 64 + d], acc);
    red[t] = acc;
    __syncthreads();
    if (t < 64) {
        const float s4 = red[t] + red[t + 64] + red[t + 128] + red[t + 192];
        x_new[row * 64 + t] = bve[t] + VnWve[row * 64 + t] * (1.f - g) + s4;
    }
}

extern "C" void kernel_launch(void* const* d_in, const int* in_sizes, int n_in,
                              void* d_out, int out_size, void* d_ws, size_t ws_size,
                              hipStream_t stream) {
    const float* x   = (const float*)d_in[0];
    const float* e   = (const float*)d_in[1];
    const float* Wq1 = (const float*)d_in[2];  const float* bq1 = (const float*)d_in[3];
    const float* Wk1 = (const float*)d_in[4];  const float* bk1 = (const float*)d_in[5];
    const float* Wv1 = (const float*)d_in[6];  const float* bv1 = (const float*)d_in[7];
    const float* Wqe = (const float*)d_in[8];  const float* bqe = (const float*)d_in[9];
    const float* Wkn = (const float*)d_in[10]; const float* bkn = (const float*)d_in[11];
    const float* Wvn = (const float*)d_in[12]; const float* bvn = (const float*)d_in[13];
    const float* Wqn = (const float*)d_in[14]; const float* bqn = (const float*)d_in[15];
    const float* Wke = (const float*)d_in[16]; /* bke cancels in softmax */
    const float* Wve = (const float*)d_in[18]; const float* bve = (const float*)d_in[19];

    float* out = (float*)d_out;
    float* x_new = out;                 // (2,512,64)
    float* e_new = out + 2 * NN * 64;   // (2,512,512,64)

    // workspace layout (floats)
    float* ws = (float*)d_ws;
    const int R = 2 * NN;               // 1024 rows of 64
    float* Q     = ws;                  // R*64
    float* K     = Q + R * 64;
    float* V     = K + R * 64;
    float* xhat  = V + R * 64;
    float* Kn    = xhat + R * 64;
    float* Vn    = Kn + R * 64;
    float* Qn    = Vn + R * 64;
    float* P     = Qn + R * 64;
    float* q0    = P + R * 64;          // R
    float* VnWke = q0 + R;
    float* VnWve = VnWke + R * 64;
    float* Ai    = VnWve + R * 64;      // 2*512*512

    proj3_kernel<<<R, 64, 0, stream>>>(x, Wq1, bq1, Wk1, bk1, Wv1, bv1, Q, K, V);
    selfattn_kernel<<<R, 256, 0, stream>>>(Q, K, V, xhat);
    proj3_kernel<<<R, 64, 0, stream>>>(xhat, Wkn, bkn, Wvn, bvn, Wqn, bqn, Kn, Vn, Qn);
    derive_kernel<<<R, 64, 0, stream>>>(Kn, Vn, Wqe, bqe, Wke, Wve, P, q0, VnWke, VnWve);
    edge_kernel<<<(2 * NN * NN) / 16, 256, 0, stream>>>(e, P, q0, Vn, e_new, Ai);
    node_kernel<<<R, 256, 0, stream>>>(Qn, VnWke, VnWve, bve, Ai, x_new);
}

// Round 3
// 159.296 us; speedup vs baseline: 1.0206x; 1.0206x over previous
//
#include <hip/hip_runtime.h>
#include <math.h>

// B=2, N=512, D=64, DH=64
#define NN 512
#define DH 64

typedef float f4 __attribute__((ext_vector_type(4)));  // native vec for nontemporal builtins

// ---------- generic 3-way projection: out_k = in @ W_k + b_k, rows of 64 ----------
__global__ __launch_bounds__(64) void proj3_kernel(
    const float* __restrict__ in,
    const float* __restrict__ W0, const float* __restrict__ b0,
    const float* __restrict__ W1, const float* __restrict__ b1,
    const float* __restrict__ W2, const float* __restrict__ b2,
    float* __restrict__ o0, float* __restrict__ o1, float* __restrict__ o2)
{
    const int row = blockIdx.x;
    const int d = threadIdx.x;
    __shared__ float xr[64];
    xr[d] = in[row * 64 + d];
    __syncthreads();
    float a0 = b0[d], a1 = b1[d], a2 = b2[d];
#pragma unroll
    for (int k = 0; k < 64; ++k) {
        const float xv = xr[k];
        a0 = fmaf(xv, W0[k * 64 + d], a0);
        a1 = fmaf(xv, W1[k * 64 + d], a1);
        a2 = fmaf(xv, W2[k * 64 + d], a2);
    }
    o0[row * 64 + d] = a0;
    o1[row * 64 + d] = a1;
    o2[row * 64 + d] = a2;
}

// ---------- node-to-node self attention: x_hat = softmax(QK^T/8) @ V ----------
__global__ __launch_bounds__(256) void selfattn_kernel(
    const float* __restrict__ Q, const float* __restrict__ K,
    const float* __restrict__ V, float* __restrict__ xhat)
{
    const int row = blockIdx.x;            // b*512 + n
    const int b = row >> 9;
    const int t = threadIdx.x;
    __shared__ float qr[64];
    __shared__ float p[512];
    __shared__ float red[256];
    if (t < 64) qr[t] = Q[row * 64 + t];
    __syncthreads();
    for (int m = t; m < NN; m += 256) {
        const float4* kr = (const float4*)(K + (b * NN + m) * 64);
        float s = 0.f;
#pragma unroll
        for (int k2 = 0; k2 < 16; ++k2) {
            float4 w = kr[k2];
            const float* q4 = qr + k2 * 4;
            s += q4[0] * w.x + q4[1] * w.y + q4[2] * w.z + q4[3] * w.w;
        }
        p[m] = s * 0.125f;
    }
    __syncthreads();
    float v0 = p[t], v1 = p[t + 256];
    red[t] = fmaxf(v0, v1);
    __syncthreads();
    for (int o = 128; o; o >>= 1) { if (t < o) red[t] = fmaxf(red[t], red[t + o]); __syncthreads(); }
    const float mx = red[0];
    __syncthreads();
    const float e0 = expf(v0 - mx), e1 = expf(v1 - mx);
    p[t] = e0; p[t + 256] = e1;
    red[t] = e0 + e1;
    __syncthreads();
    for (int o = 128; o; o >>= 1) { if (t < o) red[t] += red[t + o]; __syncthreads(); }
    const float inv = 1.f / red[0];
    __syncthreads();
    const int d = t & 63, q = t >> 6;
    float acc = 0.f;
    const int m0 = q * 128;
    for (int m = m0; m < m0 + 128; ++m)
        acc = fmaf(p[m], V[(b * NN + m) * 64 + d], acc);
    red[t] = acc;
    __syncthreads();
    if (t < 64)
        xhat[row * 64 + t] = (red[t] + red[t + 64] + red[t + 128] + red[t + 192]) * inv;
}

// ---------- fused: Kn,Vn,Qn projections + derived tensors P,q0,VnWke,VnWve ----------
__global__ __launch_bounds__(64) void projderive_kernel(
    const float* __restrict__ xhat,
    const float* __restrict__ Wkn, const float* __restrict__ bkn,
    const float* __restrict__ Wvn, const float* __restrict__ bvn,
    const float* __restrict__ Wqn, const float* __restrict__ bqn,
    const float* __restrict__ Wqe, const float* __restrict__ bqe,
    const float* __restrict__ Wke, const float* __restrict__ Wve,
    float* __restrict__ Qn, float* __restrict__ Vn,
    float* __restrict__ P, float* __restrict__ q0,
    float* __restrict__ VnWke, float* __restrict__ VnWve)
{
    const int row = blockIdx.x;
    const int d = threadIdx.x;
    __shared__ float xr[64], knr[64], vnr[64], red[64];
    xr[d] = xhat[row * 64 + d];
    __syncthreads();
    float kn = bkn[d], vn = bvn[d], qnv = bqn[d];
#pragma unroll
    for (int k = 0; k < 64; ++k) {
        const float xv = xr[k];
        kn  = fmaf(xv, Wkn[k * 64 + d], kn);
        vn  = fmaf(xv, Wvn[k * 64 + d], vn);
        qnv = fmaf(xv, Wqn[k * 64 + d], qnv);
    }
    knr[d] = kn; vnr[d] = vn;
    Qn[row * 64 + d] = qnv;
    Vn[row * 64 + d] = vn;
    __syncthreads();
    float pd = 0.f, ake = 0.f, ave = 0.f;
#pragma unroll
    for (int k = 0; k < 64; ++k) {
        pd  = fmaf(Wqe[d * 64 + k], knr[k], pd);
        ake = fmaf(vnr[k], Wke[k * 64 + d], ake);
        ave = fmaf(vnr[k], Wve[k * 64 + d], ave);
    }
    P[row * 64 + d] = pd;
    VnWke[row * 64 + d] = ake;
    VnWve[row * 64 + d] = ave;
    red[d] = bqe[d] * knr[d];
    __syncthreads();
    for (int o = 32; o; o >>= 1) { if (d < o) red[d] += red[d + o]; __syncthreads(); }
    if (d == 0) q0[row] = red[0] * 0.125f;
}

// ---------- fused edge stream + edge-to-node: e_new, Ai (LDS only), x_new ----------
__global__ __launch_bounds__(256) void edgenode_kernel(
    const float* __restrict__ e, const float* __restrict__ P,
    const float* __restrict__ q0, const float* __restrict__ Vn,
    const float* __restrict__ Qn, const float* __restrict__ VnWke,
    const float* __restrict__ VnWve, const float* __restrict__ bve,
    float* __restrict__ e_new, float* __restrict__ x_new)
{
    const int bi = blockIdx.x;       // b*512 + i
    const int b = bi >> 9, i = bi & 511;
    const int t = threadIdx.x;
    const int r = t >> 4;            // 16 rows (j's) per chunk
    const int k = t & 15;            // float4 lane within row

    __shared__ float qn[64], pis[64], vis[64];
    __shared__ float as[512], us[512], cs[512];
    __shared__ float red[256];

    if (t < 64) {
        qn[t]  = Qn[bi * 64 + t];
        pis[t] = P[bi * 64 + t];
        vis[t] = Vn[bi * 64 + t];
    }
    __syncthreads();
    const float q0i = q0[bi];
    const float4 pi4 = ((const float4*)pis)[k];
    const float4 vi4 = ((const float4*)vis)[k];
    const float4 qn4 = ((const float4*)qn)[k];

    const f4* erow  = (const f4*)(e     + (size_t)bi * NN * 64);
    f4*       enrow = (f4*)      (e_new + (size_t)bi * NN * 64);

    // phase 1: stream e -> e_new, produce as[j] (=Ai) and us[j] (=Qn.VnWke_j/8)
    for (int c0 = 0; c0 < 32; ++c0) {
        const int j  = c0 * 16 + r;
        const int bj = b * NN + j;
        const f4 ev = __builtin_nontemporal_load(erow + j * 16 + k);
        const float4 pj = ((const float4*)P)[bj * 16 + k];
        const float4 wj = ((const float4*)VnWke)[bj * 16 + k];
        float s = ev.x * (pj.x - pi4.x) + ev.y * (pj.y - pi4.y)
                + ev.z * (pj.z - pi4.z) + ev.w * (pj.w - pi4.w);
        float uu = qn4.x * wj.x + qn4.y * wj.y + qn4.z * wj.z + qn4.w * wj.w;
        s  += __shfl_xor(s, 1);  uu += __shfl_xor(uu, 1);
        s  += __shfl_xor(s, 2);  uu += __shfl_xor(uu, 2);
        s  += __shfl_xor(s, 4);  uu += __shfl_xor(uu, 4);
        s  += __shfl_xor(s, 8);  uu += __shfl_xor(uu, 8);
        const float ai = 1.f / (1.f + expf(-(s * 0.125f + q0[bj] - q0i)));
        const float4 vj = ((const float4*)Vn)[bj * 16 + k];
        f4 en;
        en.x = fmaf(ai, vj.x - vi4.x, vi4.x);
        en.y = fmaf(ai, vj.y - vi4.y, vi4.y);
        en.z = fmaf(ai, vj.z - vi4.z, vi4.z);
        en.w = fmaf(ai, vj.w - vi4.w, vi4.w);
        __builtin_nontemporal_store(en, enrow + j * 16 + k);
        if (k == 0) { as[j] = ai; us[j] = uu * 0.125f; }
    }
    __syncthreads();

    // phase 2: row softmax over v_j = Ai_j*(u_j - u_i), then PV
    const int lane = t & 63, w = t >> 6;
    const float uii = us[i];
    const float v0 = as[t] * (us[t] - uii);
    const float v1 = as[t + 256] * (us[t + 256] - uii);
    float m = fmaxf(v0, v1);
#pragma unroll
    for (int o = 1; o < 64; o <<= 1) m = fmaxf(m, __shfl_xor(m, o));
    if (lane == 0) red[w] = m;
    __syncthreads();
    const float mx = fmaxf(fmaxf(red[0], red[1]), fmaxf(red[2], red[3]));
    const float e0 = expf(v0 - mx), e1 = expf(v1 - mx);
    float ss = e0 + e1;
#pragma unroll
    for (int o = 1; o < 64; o <<= 1) ss += __shfl_xor(ss, o);
    if (lane == 0) red[4 + w] = ss;
    __syncthreads();
    const float inv = 1.f / (red[4] + red[5] + red[6] + red[7]);
    const float c0v = e0 * inv * as[t];
    const float c1v = e1 * inv * as[t + 256];
    cs[t] = c0v; cs[t + 256] = c1v;
    float gg = c0v + c1v;
#pragma unroll
    for (int o = 1; o < 64; o <<= 1) gg += __shfl_xor(gg, o);
    if (lane == 0) red[8 + w] = gg;
    __syncthreads();
    const float g = red[8] + red[9] + red[10] + red[11];
    __syncthreads();                     // protect red[] before reuse

    const int d = t & 63, q = t >> 6;
    float acc = 0.f;
    const int j0 = q * 128;
    for (int j = j0; j < j0 + 128; ++j)
        acc = fmaf(cs[j], VnWve[(b * NN + j) * 64 + d], acc);
    red[t] = acc;
    __syncthreads();
    if (t < 64) {
        const float s4 = red[t] + red[t + 64] + red[t + 128] + red[t + 192];
        x_new[bi * 64 + t] = bve[t] + VnWve[bi * 64 + t] * (1.f - g) + s4;
    }
}

extern "C" void kernel_launch(void* const* d_in, const int* in_sizes, int n_in,
                              void* d_out, int out_size, void* d_ws, size_t ws_size,
                              hipStream_t stream) {
    const float* x   = (const float*)d_in[0];
    const float* e   = (const float*)d_in[1];
    const float* Wq1 = (const float*)d_in[2];  const float* bq1 = (const float*)d_in[3];
    const float* Wk1 = (const float*)d_in[4];  const float* bk1 = (const float*)d_in[5];
    const float* Wv1 = (const float*)d_in[6];  const float* bv1 = (const float*)d_in[7];
    const float* Wqe = (const float*)d_in[8];  const float* bqe = (const float*)d_in[9];
    const float* Wkn = (const float*)d_in[10]; const float* bkn = (const float*)d_in[11];
    const float* Wvn = (const float*)d_in[12]; const float* bvn = (const float*)d_in[13];
    const float* Wqn = (const float*)d_in[14]; const float* bqn = (const float*)d_in[15];
    const float* Wke = (const float*)d_in[16]; /* bke cancels in softmax */
    const float* Wve = (const float*)d_in[18]; const float* bve = (const float*)d_in[19];

    float* out = (float*)d_out;
    float* x_new = out;                 // (2,512,64)
    float* e_new = out + 2 * NN * 64;   // (2,512,512,64)

    float* ws = (float*)d_ws;
    const int R = 2 * NN;               // 1024 rows of 64
    float* Q     = ws;                  // R*64 each
    float* K     = Q + R * 64;
    float* V     = K + R * 64;
    float* xhat  = V + R * 64;
    float* Qn    = xhat + R * 64;
    float* Vn    = Qn + R * 64;
    float* P     = Vn + R * 64;
    float* VnWke = P + R * 64;
    float* VnWve = VnWke + R * 64;
    float* q0    = VnWve + R * 64;      // R

    proj3_kernel<<<R, 64, 0, stream>>>(x, Wq1, bq1, Wk1, bk1, Wv1, bv1, Q, K, V);
    selfattn_kernel<<<R, 256, 0, stream>>>(Q, K, V, xhat);
    projderive_kernel<<<R, 64, 0, stream>>>(xhat, Wkn, bkn, Wvn, bvn, Wqn, bqn,
                                            Wqe, bqe, Wke, Wve,
                                            Qn, Vn, P, q0, VnWke, VnWve);
    edgenode_kernel<<<R, 256, 0, stream>>>(e, P, q0, Vn, Qn, VnWke, VnWve, bve,
                                           e_new, x_new);
}

// Round 4
// 148.231 us; speedup vs baseline: 1.0968x; 1.0747x over previous
//
#include <hip/hip_runtime.h>
#include <math.h>

// B=2, N=512, D=64, DH=64
#define NN 512

typedef float f4 __attribute__((ext_vector_type(4)));  // native vec for nontemporal builtins

// ---------------- precompute weight products (runs once per launch, 3 blocks) ----------------
// m=0: M_P  = Wkn @ Wqe^T ; c_P  = bkn @ Wqe^T ; vq0 = 0.125*(Wkn @ bqe) ; s0 = 0.125*(bqe.bkn)
// m=1: M_ke = Wvn @ Wke   ; c_ke = bvn @ Wke
// m=2: M_ve = Wvn @ Wve   ; c_ve = bvn @ Wve
__global__ __launch_bounds__(256) void precompute_kernel(
    const float* __restrict__ Wkn, const float* __restrict__ bkn,
    const float* __restrict__ Wvn, const float* __restrict__ bvn,
    const float* __restrict__ Wqe, const float* __restrict__ bqe,
    const float* __restrict__ Wke, const float* __restrict__ Wve,
    float* __restrict__ M_P, float* __restrict__ c_P,
    float* __restrict__ M_ke, float* __restrict__ c_ke,
    float* __restrict__ M_ve, float* __restrict__ c_ve,
    float* __restrict__ vq0, float* __restrict__ s0p)
{
    const int m = blockIdx.x;
    const int t = threadIdx.x;
    __shared__ float As[64 * 65];   // A row-major, padded
    __shared__ float Bs[64 * 65];   // Bs[b][k] = B-operand with dot axis k
    __shared__ float va[64], vb[64];
    const float* A  = (m == 0) ? Wkn : Wvn;
    const float* aV = (m == 0) ? bkn : bvn;
    const float* B  = (m == 0) ? Wqe : (m == 1 ? Wke : Wve);

#pragma unroll
    for (int p = 0; p < 16; ++p) {
        const int idx = p * 256 + t;           // 4096 elements
        const int r = idx >> 6, cc = idx & 63;
        As[r * 65 + cc] = A[idx];
        if (m == 0) Bs[r * 65 + cc] = B[idx];  // Wqe[b][k] already dot-over-k layout
        else        Bs[cc * 65 + r] = B[idx];  // transpose Wke/Wve: Bs[b][k] = B[k][b]
    }
    if (t < 64) { va[t] = aV[t]; vb[t] = bqe[t]; }
    __syncthreads();

    const int b = t & 63, g = t >> 6;          // thread: column b, 16 rows (g*16..)
    float acc[16];
#pragma unroll
    for (int aa = 0; aa < 16; ++aa) acc[aa] = 0.f;
    for (int k = 0; k < 64; ++k) {
        const float bv = Bs[b * 65 + k];       // banks (b+k)%32: conflict-free
#pragma unroll
        for (int aa = 0; aa < 16; ++aa)        // As read is wave-broadcast
            acc[aa] = fmaf(As[(g * 16 + aa) * 65 + k], bv, acc[aa]);
    }
    float* M = (m == 0) ? M_P : (m == 1 ? M_ke : M_ve);
#pragma unroll
    for (int aa = 0; aa < 16; ++aa)
        M[(g * 16 + aa) * 64 + b] = acc[aa];

    if (t < 64) {
        float cb = 0.f;
        for (int k = 0; k < 64; ++k) cb = fmaf(va[k], Bs[t * 65 + k], cb);
        float* C = (m == 0) ? c_P : (m == 1 ? c_ke : c_ve);
        C[t] = cb;
        if (m == 0) {
            float q = 0.f;
            for (int k = 0; k < 64; ++k) q = fmaf(As[t * 65 + k], vb[k], q);
            vq0[t] = q * 0.125f;
        }
    }
    if (m == 0 && t == 0) {
        float s = 0.f;
        for (int k = 0; k < 64; ++k) s += vb[k] * va[k];
        *s0p = s * 0.125f;
    }
}

// ---------------- tiled 3-way projection: 32 rows/block, weights in LDS ----------------
__global__ __launch_bounds__(256) void proj3_tiled(
    const float* __restrict__ in,
    const float* __restrict__ W0, const float* __restrict__ b0,
    const float* __restrict__ W1, const float* __restrict__ b1,
    const float* __restrict__ W2, const float* __restrict__ b2,
    float* __restrict__ o0, float* __restrict__ o1, float* __restrict__ o2)
{
    const int t = threadIdx.x;
    const int rb = blockIdx.x * 32;
    __shared__ float Ws0[4096], Ws1[4096], Ws2[4096];
    __shared__ float xs[2048];
    __shared__ float bs0[64], bs1[64], bs2[64];
#pragma unroll
    for (int p = 0; p < 4; ++p) {
        const int idx = p * 256 + t;
        ((f4*)Ws0)[idx] = ((const f4*)W0)[idx];
        ((f4*)Ws1)[idx] = ((const f4*)W1)[idx];
        ((f4*)Ws2)[idx] = ((const f4*)W2)[idx];
    }
    ((f4*)xs)[t]       = ((const f4*)(in + rb * 64))[t];
    ((f4*)xs)[t + 256] = ((const f4*)(in + rb * 64))[t + 256];
    if (t < 64) { bs0[t] = b0[t]; bs1[t] = b1[t]; bs2[t] = b2[t]; }
    __syncthreads();

    const int d = t & 63, g = t >> 6;          // wave g owns rows g*8..g*8+7
    float a0[8], a1[8], a2[8];
#pragma unroll
    for (int r = 0; r < 8; ++r) { a0[r] = bs0[d]; a1[r] = bs1[d]; a2[r] = bs2[d]; }
    for (int k4 = 0; k4 < 16; ++k4) {
        float w0[4], w1[4], w2[4];
#pragma unroll
        for (int kk = 0; kk < 4; ++kk) {
            w0[kk] = Ws0[(k4 * 4 + kk) * 64 + d];
            w1[kk] = Ws1[(k4 * 4 + kk) * 64 + d];
            w2[kk] = Ws2[(k4 * 4 + kk) * 64 + d];
        }
#pragma unroll
        for (int r = 0; r < 8; ++r) {
            const f4 xv = ((const f4*)xs)[(g * 8 + r) * 16 + k4];  // wave-broadcast b128
            a0[r] = fmaf(xv.x, w0[0], fmaf(xv.y, w0[1], fmaf(xv.z, w0[2], fmaf(xv.w, w0[3], a0[r]))));
            a1[r] = fmaf(xv.x, w1[0], fmaf(xv.y, w1[1], fmaf(xv.z, w1[2], fmaf(xv.w, w1[3], a1[r]))));
            a2[r] = fmaf(xv.x, w2[0], fmaf(xv.y, w2[1], fmaf(xv.z, w2[2], fmaf(xv.w, w2[3], a2[r]))));
        }
    }
#pragma unroll
    for (int r = 0; r < 8; ++r) {
        o0[(rb + g * 8 + r) * 64 + d] = a0[r];
        o1[(rb + g * 8 + r) * 64 + d] = a1[r];
        o2[(rb + g * 8 + r) * 64 + d] = a2[r];
    }
}

// ---------- node-to-node self attention: x_hat = softmax(QK^T/8) @ V ----------
__global__ __launch_bounds__(256) void selfattn_kernel(
    const float* __restrict__ Q, const float* __restrict__ K,
    const float* __restrict__ V, float* __restrict__ xhat)
{
    const int row = blockIdx.x;            // b*512 + n
    const int b = row >> 9;
    const int t = threadIdx.x;
    __shared__ float qr[64];
    __shared__ float p[512];
    __shared__ float red[256];
    if (t < 64) qr[t] = Q[row * 64 + t];
    __syncthreads();
    for (int m = t; m < NN; m += 256) {
        const float4* kr = (const float4*)(K + (b * NN + m) * 64);
        float s = 0.f;
#pragma unroll
        for (int k2 = 0; k2 < 16; ++k2) {
            float4 w = kr[k2];
            const float* q4 = qr + k2 * 4;
            s += q4[0] * w.x + q4[1] * w.y + q4[2] * w.z + q4[3] * w.w;
        }
        p[m] = s * 0.125f;
    }
    __syncthreads();
    float v0 = p[t], v1 = p[t + 256];
    red[t] = fmaxf(v0, v1);
    __syncthreads();
    for (int o = 128; o; o >>= 1) { if (t < o) red[t] = fmaxf(red[t], red[t + o]); __syncthreads(); }
    const float mx = red[0];
    __syncthreads();
    const float e0 = expf(v0 - mx), e1 = expf(v1 - mx);
    p[t] = e0; p[t + 256] = e1;
    red[t] = e0 + e1;
    __syncthreads();
    for (int o = 128; o; o >>= 1) { if (t < o) red[t] += red[t + o]; __syncthreads(); }
    const float inv = 1.f / red[0];
    __syncthreads();
    const int d = t & 63, q = t >> 6;
    float acc = 0.f;
    const int m0 = q * 128;
    for (int m = m0; m < m0 + 128; ++m)
        acc = fmaf(p[m], V[(b * NN + m) * 64 + d], acc);
    red[t] = acc;
    __syncthreads();
    if (t < 64)
        xhat[row * 64 + t] = (red[t] + red[t + 64] + red[t + 128] + red[t + 192]) * inv;
}

// ---------------- fused affine maps of xhat: Qn, Vn, P, VnWke, VnWve, q0 ----------------
__global__ __launch_bounds__(256) void affine5_kernel(
    const float* __restrict__ xhat,
    const float* __restrict__ Wqn, const float* __restrict__ bqn,
    const float* __restrict__ Wvn, const float* __restrict__ bvn,
    const float* __restrict__ M_P, const float* __restrict__ c_P,
    const float* __restrict__ M_ke, const float* __restrict__ c_ke,
    const float* __restrict__ M_ve, const float* __restrict__ c_ve,
    const float* __restrict__ vq0, const float* __restrict__ s0p,
    float* __restrict__ Qn, float* __restrict__ Vn, float* __restrict__ P,
    float* __restrict__ VnWke, float* __restrict__ VnWve, float* __restrict__ q0)
{
    const int t = threadIdx.x;
    const int rb = blockIdx.x * 32;
    const int m = blockIdx.y;
    const float* W; const float* c; float* o;
    if (m == 0)      { W = Wqn;  c = bqn;  o = Qn; }
    else if (m == 1) { W = Wvn;  c = bvn;  o = Vn; }
    else if (m == 2) { W = M_P;  c = c_P;  o = P; }
    else if (m == 3) { W = M_ke; c = c_ke; o = VnWke; }
    else             { W = M_ve; c = c_ve; o = VnWve; }
    __shared__ float Ws[4096], xs[2048], cs[64], vq0s[64];
#pragma unroll
    for (int p = 0; p < 4; ++p) ((f4*)Ws)[p * 256 + t] = ((const f4*)W)[p * 256 + t];
    ((f4*)xs)[t]       = ((const f4*)(xhat + rb * 64))[t];
    ((f4*)xs)[t + 256] = ((const f4*)(xhat + rb * 64))[t + 256];
    if (t < 64) { cs[t] = c[t]; if (m == 0) vq0s[t] = vq0[t]; }
    __syncthreads();

    const int d = t & 63, g = t >> 6;
    float acc[8];
#pragma unroll
    for (int r = 0; r < 8; ++r) acc[r] = cs[d];
    for (int k4 = 0; k4 < 16; ++k4) {
        float w[4];
#pragma unroll
        for (int kk = 0; kk < 4; ++kk) w[kk] = Ws[(k4 * 4 + kk) * 64 + d];
#pragma unroll
        for (int r = 0; r < 8; ++r) {
            const f4 xv = ((const f4*)xs)[(g * 8 + r) * 16 + k4];
            acc[r] = fmaf(xv.x, w[0], fmaf(xv.y, w[1], fmaf(xv.z, w[2], fmaf(xv.w, w[3], acc[r]))));
        }
    }
#pragma unroll
    for (int r = 0; r < 8; ++r) o[(rb + g * 8 + r) * 64 + d] = acc[r];

    if (m == 0) {
        // q0[rb+row] = s0 + xhat_row . vq0 ; row = t>>3, 8-lane segments
        const int row = t >> 3, seg = t & 7;
        float part = 0.f;
#pragma unroll
        for (int kk = 0; kk < 8; ++kk)
            part = fmaf(xs[row * 64 + seg * 8 + kk], vq0s[seg * 8 + kk], part);
        part += __shfl_xor(part, 1);
        part += __shfl_xor(part, 2);
        part += __shfl_xor(part, 4);
        if (seg == 0) q0[rb + row] = part + s0p[0];
    }
}

// ---------- fused edge stream + edge-to-node: e_new, Ai (LDS only), x_new ----------
__global__ __launch_bounds__(256) void edgenode_kernel(
    const float* __restrict__ e, const float* __restrict__ P,
    const float* __restrict__ q0, const float* __restrict__ Vn,
    const float* __restrict__ Qn, const float* __restrict__ VnWke,
    const float* __restrict__ VnWve, const float* __restrict__ bve,
    float* __restrict__ e_new, float* __restrict__ x_new)
{
    const int bi = blockIdx.x;       // b*512 + i
    const int b = bi >> 9, i = bi & 511;
    const int t = threadIdx.x;
    const int r = t >> 4;            // 16 rows (j's) per chunk
    const int k = t & 15;            // float4 lane within row

    __shared__ float qn[64], pis[64], vis[64];
    __shared__ float as[512], us[512], cs[512];
    __shared__ float red[256];

    if (t < 64) {
        qn[t]  = Qn[bi * 64 + t];
        pis[t] = P[bi * 64 + t];
        vis[t] = Vn[bi * 64 + t];
    }
    __syncthreads();
    const float q0i = q0[bi];
    const float4 pi4 = ((const float4*)pis)[k];
    const float4 vi4 = ((const float4*)vis)[k];
    const float4 qn4 = ((const float4*)qn)[k];

    const f4* erow  = (const f4*)(e     + (size_t)bi * NN * 64);
    f4*       enrow = (f4*)      (e_new + (size_t)bi * NN * 64);

    // phase 1: stream e -> e_new, produce as[j] (=Ai) and us[j] (=Qn.VnWke_j/8)
    for (int c0 = 0; c0 < 32; ++c0) {
        const int j  = c0 * 16 + r;
        const int bj = b * NN + j;
        const f4 ev = __builtin_nontemporal_load(erow + j * 16 + k);
        const float4 pj = ((const float4*)P)[bj * 16 + k];
        const float4 wj = ((const float4*)VnWke)[bj * 16 + k];
        float s = ev.x * (pj.x - pi4.x) + ev.y * (pj.y - pi4.y)
                + ev.z * (pj.z - pi4.z) + ev.w * (pj.w - pi4.w);
        float uu = qn4.x * wj.x + qn4.y * wj.y + qn4.z * wj.z + qn4.w * wj.w;
        s  += __shfl_xor(s, 1);  uu += __shfl_xor(uu, 1);
        s  += __shfl_xor(s, 2);  uu += __shfl_xor(uu, 2);
        s  += __shfl_xor(s, 4);  uu += __shfl_xor(uu, 4);
        s  += __shfl_xor(s, 8);  uu += __shfl_xor(uu, 8);
        const float ai = 1.f / (1.f + expf(-(s * 0.125f + q0[bj] - q0i)));
        const float4 vj = ((const float4*)Vn)[bj * 16 + k];
        f4 en;
        en.x = fmaf(ai, vj.x - vi4.x, vi4.x);
        en.y = fmaf(ai, vj.y - vi4.y, vi4.y);
        en.z = fmaf(ai, vj.z - vi4.z, vi4.z);
        en.w = fmaf(ai, vj.w - vi4.w, vi4.w);
        __builtin_nontemporal_store(en, enrow + j * 16 + k);
        if (k == 0) { as[j] = ai; us[j] = uu * 0.125f; }
    }
    __syncthreads();

    // phase 2: row softmax over v_j = Ai_j*(u_j - u_i), then PV
    const int lane = t & 63, w = t >> 6;
    const float uii = us[i];
    const float v0 = as[t] * (us[t] - uii);
    const float v1 = as[t + 256] * (us[t + 256] - uii);
    float m = fmaxf(v0, v1);
#pragma unroll
    for (int o = 1; o < 64; o <<= 1) m = fmaxf(m, __shfl_xor(m, o));
    if (lane == 0) red[w] = m;
    __syncthreads();
    const float mx = fmaxf(fmaxf(red[0], red[1]), fmaxf(red[2], red[3]));
    const float e0 = expf(v0 - mx), e1 = expf(v1 - mx);
    float ss = e0 + e1;
#pragma unroll
    for (int o = 1; o < 64; o <<= 1) ss += __shfl_xor(ss, o);
    if (lane == 0) red[4 + w] = ss;
    __syncthreads();
    const float inv = 1.f / (red[4] + red[5] + red[6] + red[7]);
    const float c0v = e0 * inv * as[t];
    const float c1v = e1 * inv * as[t + 256];
    cs[t] = c0v; cs[t + 256] = c1v;
    float gg = c0v + c1v;
#pragma unroll
    for (int o = 1; o < 64; o <<= 1) gg += __shfl_xor(gg, o);
    if (lane == 0) red[8 + w] = gg;
    __syncthreads();
    const float g = red[8] + red[9] + red[10] + red[11];
    __syncthreads();                     // protect red[] before reuse

    const int d = t & 63, q = t >> 6;
    float acc = 0.f;
    const int j0 = q * 128;
    for (int j = j0; j < j0 + 128; ++j)
        acc = fmaf(cs[j], VnWve[(b * NN + j) * 64 + d], acc);
    red[t] = acc;
    __syncthreads();
    if (t < 64) {
        const float s4 = red[t] + red[t + 64] + red[t + 128] + red[t + 192];
        x_new[bi * 64 + t] = bve[t] + VnWve[bi * 64 + t] * (1.f - g) + s4;
    }
}

extern "C" void kernel_launch(void* const* d_in, const int* in_sizes, int n_in,
                              void* d_out, int out_size, void* d_ws, size_t ws_size,
                              hipStream_t stream) {
    const float* x   = (const float*)d_in[0];
    const float* e   = (const float*)d_in[1];
    const float* Wq1 = (const float*)d_in[2];  const float* bq1 = (const float*)d_in[3];
    const float* Wk1 = (const float*)d_in[4];  const float* bk1 = (const float*)d_in[5];
    const float* Wv1 = (const float*)d_in[6];  const float* bv1 = (const float*)d_in[7];
    const float* Wqe = (const float*)d_in[8];  const float* bqe = (const float*)d_in[9];
    const float* Wkn = (const float*)d_in[10]; const float* bkn = (const float*)d_in[11];
    const float* Wvn = (const float*)d_in[12]; const float* bvn = (const float*)d_in[13];
    const float* Wqn = (const float*)d_in[14]; const float* bqn = (const float*)d_in[15];
    const float* Wke = (const float*)d_in[16]; /* bke cancels in softmax */
    const float* Wve = (const float*)d_in[18]; const float* bve = (const float*)d_in[19];

    float* out = (float*)d_out;
    float* x_new = out;                 // (2,512,64)
    float* e_new = out + 2 * NN * 64;   // (2,512,512,64)

    float* ws = (float*)d_ws;
    const int R = 2 * NN;               // 1024 rows of 64
    float* Q     = ws;                  // R*64 each
    float* K     = Q + R * 64;
    float* V     = K + R * 64;
    float* xhat  = V + R * 64;
    float* Qn    = xhat + R * 64;
    float* Vn    = Qn + R * 64;
    float* P     = Vn + R * 64;
    float* VnWke = P + R * 64;
    float* VnWve = VnWke + R * 64;
    float* q0    = VnWve + R * 64;      // R
    float* M_P   = q0 + R;              // 4096 each
    float* M_ke  = M_P + 4096;
    float* M_ve  = M_ke + 4096;
    float* c_P   = M_ve + 4096;         // 64 each
    float* c_ke  = c_P + 64;
    float* c_ve  = c_ke + 64;
    float* vq0   = c_ve + 64;
    float* s0    = vq0 + 64;            // 1

    precompute_kernel<<<3, 256, 0, stream>>>(Wkn, bkn, Wvn, bvn, Wqe, bqe, Wke, Wve,
                                             M_P, c_P, M_ke, c_ke, M_ve, c_ve, vq0, s0);
    proj3_tiled<<<32, 256, 0, stream>>>(x, Wq1, bq1, Wk1, bk1, Wv1, bv1, Q, K, V);
    selfattn_kernel<<<R, 256, 0, stream>>>(Q, K, V, xhat);
    affine5_kernel<<<dim3(32, 5), 256, 0, stream>>>(xhat, Wqn, bqn, Wvn, bvn,
                                                    M_P, c_P, M_ke, c_ke, M_ve, c_ve,
                                                    vq0, s0,
                                                    Qn, Vn, P, VnWke, VnWve, q0);
    edgenode_kernel<<<R, 256, 0, stream>>>(e, P, q0, Vn, Qn, VnWke, VnWve, bve,
                                           e_new, x_new);
}

// Round 5
// 95.911 us; speedup vs baseline: 1.6950x; 1.5455x over previous
//
#include <hip/hip_runtime.h>
#include <math.h>

// B=2, N=512, D=64, DH=64
#define NN 512

typedef float f4 __attribute__((ext_vector_type(4)));  // native vec for nontemporal builtins

// ---------------- precompute weight products (runs once per launch, 3 blocks) ----------------
// m=0: M_P  = Wkn @ Wqe^T ; c_P  = bkn @ Wqe^T ; vq0 = 0.125*(Wkn @ bqe) ; s0 = 0.125*(bqe.bkn)
// m=1: M_ke = Wvn @ Wke   ; c_ke = bvn @ Wke
// m=2: M_ve = Wvn @ Wve   ; c_ve = bvn @ Wve
__global__ __launch_bounds__(256) void precompute_kernel(
    const float* __restrict__ Wkn, const float* __restrict__ bkn,
    const float* __restrict__ Wvn, const float* __restrict__ bvn,
    const float* __restrict__ Wqe, const float* __restrict__ bqe,
    const float* __restrict__ Wke, const float* __restrict__ Wve,
    float* __restrict__ M_P, float* __restrict__ c_P,
    float* __restrict__ M_ke, float* __restrict__ c_ke,
    float* __restrict__ M_ve, float* __restrict__ c_ve,
    float* __restrict__ vq0, float* __restrict__ s0p)
{
    const int m = blockIdx.x;
    const int t = threadIdx.x;
    __shared__ float As[64 * 65];   // A row-major, padded
    __shared__ float Bs[64 * 65];   // Bs[b][k] = B-operand with dot axis k
    __shared__ float va[64], vb[64];
    const float* A  = (m == 0) ? Wkn : Wvn;
    const float* aV = (m == 0) ? bkn : bvn;
    const float* B  = (m == 0) ? Wqe : (m == 1 ? Wke : Wve);

#pragma unroll
    for (int p = 0; p < 16; ++p) {
        const int idx = p * 256 + t;           // 4096 elements
        const int r = idx >> 6, cc = idx & 63;
        As[r * 65 + cc] = A[idx];
        if (m == 0) Bs[r * 65 + cc] = B[idx];  // Wqe[b][k] already dot-over-k layout
        else        Bs[cc * 65 + r] = B[idx];  // transpose Wke/Wve: Bs[b][k] = B[k][b]
    }
    if (t < 64) { va[t] = aV[t]; vb[t] = bqe[t]; }
    __syncthreads();

    const int b = t & 63, g = t >> 6;          // thread: column b, 16 rows (g*16..)
    float acc[16];
#pragma unroll
    for (int aa = 0; aa < 16; ++aa) acc[aa] = 0.f;
    for (int k = 0; k < 64; ++k) {
        const float bv = Bs[b * 65 + k];       // banks (b+k)%32: conflict-free
#pragma unroll
        for (int aa = 0; aa < 16; ++aa)        // As read is wave-broadcast
            acc[aa] = fmaf(As[(g * 16 + aa) * 65 + k], bv, acc[aa]);
    }
    float* M = (m == 0) ? M_P : (m == 1 ? M_ke : M_ve);
#pragma unroll
    for (int aa = 0; aa < 16; ++aa)
        M[(g * 16 + aa) * 64 + b] = acc[aa];

    if (t < 64) {
        float cb = 0.f;
        for (int k = 0; k < 64; ++k) cb = fmaf(va[k], Bs[t * 65 + k], cb);
        float* C = (m == 0) ? c_P : (m == 1 ? c_ke : c_ve);
        C[t] = cb;
        if (m == 0) {
            float q = 0.f;
            for (int k = 0; k < 64; ++k) q = fmaf(As[t * 65 + k], vb[k], q);
            vq0[t] = q * 0.125f;
        }
    }
    if (m == 0 && t == 0) {
        float s = 0.f;
        for (int k = 0; k < 64; ++k) s += vb[k] * va[k];
        *s0p = s * 0.125f;
    }
}

// ---------------- tiled 3-way projection: 32 rows/block, weights in LDS ----------------
__global__ __launch_bounds__(256) void proj3_tiled(
    const float* __restrict__ in,
    const float* __restrict__ W0, const float* __restrict__ b0,
    const float* __restrict__ W1, const float* __restrict__ b1,
    const float* __restrict__ W2, const float* __restrict__ b2,
    float* __restrict__ o0, float* __restrict__ o1, float* __restrict__ o2)
{
    const int t = threadIdx.x;
    const int rb = blockIdx.x * 32;
    __shared__ float Ws0[4096], Ws1[4096], Ws2[4096];
    __shared__ float xs[2048];
    __shared__ float bs0[64], bs1[64], bs2[64];
#pragma unroll
    for (int p = 0; p < 4; ++p) {
        const int idx = p * 256 + t;
        ((f4*)Ws0)[idx] = ((const f4*)W0)[idx];
        ((f4*)Ws1)[idx] = ((const f4*)W1)[idx];
        ((f4*)Ws2)[idx] = ((const f4*)W2)[idx];
    }
    ((f4*)xs)[t]       = ((const f4*)(in + rb * 64))[t];
    ((f4*)xs)[t + 256] = ((const f4*)(in + rb * 64))[t + 256];
    if (t < 64) { bs0[t] = b0[t]; bs1[t] = b1[t]; bs2[t] = b2[t]; }
    __syncthreads();

    const int d = t & 63, g = t >> 6;          // wave g owns rows g*8..g*8+7
    float a0[8], a1[8], a2[8];
#pragma unroll
    for (int r = 0; r < 8; ++r) { a0[r] = bs0[d]; a1[r] = bs1[d]; a2[r] = bs2[d]; }
    for (int k4 = 0; k4 < 16; ++k4) {
        float w0[4], w1[4], w2[4];
#pragma unroll
        for (int kk = 0; kk < 4; ++kk) {
            w0[kk] = Ws0[(k4 * 4 + kk) * 64 + d];
            w1[kk] = Ws1[(k4 * 4 + kk) * 64 + d];
            w2[kk] = Ws2[(k4 * 4 + kk) * 64 + d];
        }
#pragma unroll
        for (int r = 0; r < 8; ++r) {
            const f4 xv = ((const f4*)xs)[(g * 8 + r) * 16 + k4];  // wave-broadcast b128
            a0[r] = fmaf(xv.x, w0[0], fmaf(xv.y, w0[1], fmaf(xv.z, w0[2], fmaf(xv.w, w0[3], a0[r]))));
            a1[r] = fmaf(xv.x, w1[0], fmaf(xv.y, w1[1], fmaf(xv.z, w1[2], fmaf(xv.w, w1[3], a1[r]))));
            a2[r] = fmaf(xv.x, w2[0], fmaf(xv.y, w2[1], fmaf(xv.z, w2[2], fmaf(xv.w, w2[3], a2[r]))));
        }
    }
#pragma unroll
    for (int r = 0; r < 8; ++r) {
        o0[(rb + g * 8 + r) * 64 + d] = a0[r];
        o1[(rb + g * 8 + r) * 64 + d] = a1[r];
        o2[(rb + g * 8 + r) * 64 + d] = a2[r];
    }
}

// ---------- node-to-node self attention (512 thr): x_hat = softmax(QK^T/8) @ V ----------
__global__ __launch_bounds__(512) void selfattn_kernel(
    const float* __restrict__ Q, const float* __restrict__ K,
    const float* __restrict__ V, float* __restrict__ xhat)
{
    const int row = blockIdx.x;            // b*512 + n
    const int b = row >> 9;
    const int t = threadIdx.x;
    __shared__ float qr[64];
    __shared__ float p[512];
    __shared__ float red[512];
    if (t < 64) qr[t] = Q[row * 64 + t];
    __syncthreads();

    // scores: 4-lane groups, 4 passes of 128 j's
    {
        const int j4 = t >> 2, l = t & 3;
        const float4* qq = (const float4*)qr;
#pragma unroll
        for (int pass = 0; pass < 4; ++pass) {
            const int j = pass * 128 + j4;
            const float4* kr = (const float4*)(K + (size_t)(b * NN + j) * 64) + l * 4;
            float s = 0.f;
#pragma unroll
            for (int kk = 0; kk < 4; ++kk) {
                const float4 w = kr[kk];
                const float4 qv = qq[l * 4 + kk];
                s += qv.x * w.x + qv.y * w.y + qv.z * w.z + qv.w * w.w;
            }
            s += __shfl_xor(s, 1);
            s += __shfl_xor(s, 2);
            if (l == 0) p[j] = s * 0.125f;
        }
    }
    __syncthreads();

    const int lane = t & 63, w = t >> 6;
    const float v0 = p[t];
    float m = v0;
#pragma unroll
    for (int o = 1; o < 64; o <<= 1) m = fmaxf(m, __shfl_xor(m, o));
    if (lane == 0) red[w] = m;
    __syncthreads();
    float mx = red[0];
#pragma unroll
    for (int z = 1; z < 8; ++z) mx = fmaxf(mx, red[z]);
    const float e0 = expf(v0 - mx);
    float ss = e0;
#pragma unroll
    for (int o = 1; o < 64; o <<= 1) ss += __shfl_xor(ss, o);
    if (lane == 0) red[8 + w] = ss;
    __syncthreads();
    const float inv = 1.f / (red[8] + red[9] + red[10] + red[11]
                           + red[12] + red[13] + red[14] + red[15]);
    p[t] = e0;
    __syncthreads();

    const int d = t & 63, q = t >> 6;
    float acc = 0.f;
    const int j0 = q * 64;
    for (int j = j0; j < j0 + 64; ++j)
        acc = fmaf(p[j], V[(b * NN + j) * 64 + d], acc);
    red[t] = acc;
    __syncthreads();
    if (t < 64) {
        float s8 = 0.f;
#pragma unroll
        for (int z = 0; z < 8; ++z) s8 += red[t + z * 64];
        xhat[row * 64 + t] = s8 * inv;
    }
}

// ---------------- fused affine maps of xhat: Qn, Vn, P, VnWke, VnWve, q0 ----------------
__global__ __launch_bounds__(256) void affine5_kernel(
    const float* __restrict__ xhat,
    const float* __restrict__ Wqn, const float* __restrict__ bqn,
    const float* __restrict__ Wvn, const float* __restrict__ bvn,
    const float* __restrict__ M_P, const float* __restrict__ c_P,
    const float* __restrict__ M_ke, const float* __restrict__ c_ke,
    const float* __restrict__ M_ve, const float* __restrict__ c_ve,
    const float* __restrict__ vq0, const float* __restrict__ s0p,
    float* __restrict__ Qn, float* __restrict__ Vn, float* __restrict__ P,
    float* __restrict__ VnWke, float* __restrict__ VnWve, float* __restrict__ q0)
{
    const int t = threadIdx.x;
    const int rb = blockIdx.x * 32;
    const int m = blockIdx.y;
    const float* W; const float* c; float* o;
    if (m == 0)      { W = Wqn;  c = bqn;  o = Qn; }
    else if (m == 1) { W = Wvn;  c = bvn;  o = Vn; }
    else if (m == 2) { W = M_P;  c = c_P;  o = P; }
    else if (m == 3) { W = M_ke; c = c_ke; o = VnWke; }
    else             { W = M_ve; c = c_ve; o = VnWve; }
    __shared__ float Ws[4096], xs[2048], cs[64], vq0s[64];
#pragma unroll
    for (int p = 0; p < 4; ++p) ((f4*)Ws)[p * 256 + t] = ((const f4*)W)[p * 256 + t];
    ((f4*)xs)[t]       = ((const f4*)(xhat + rb * 64))[t];
    ((f4*)xs)[t + 256] = ((const f4*)(xhat + rb * 64))[t + 256];
    if (t < 64) { cs[t] = c[t]; if (m == 0) vq0s[t] = vq0[t]; }
    __syncthreads();

    const int d = t & 63, g = t >> 6;
    float acc[8];
#pragma unroll
    for (int r = 0; r < 8; ++r) acc[r] = cs[d];
    for (int k4 = 0; k4 < 16; ++k4) {
        float w[4];
#pragma unroll
        for (int kk = 0; kk < 4; ++kk) w[kk] = Ws[(k4 * 4 + kk) * 64 + d];
#pragma unroll
        for (int r = 0; r < 8; ++r) {
            const f4 xv = ((const f4*)xs)[(g * 8 + r) * 16 + k4];
            acc[r] = fmaf(xv.x, w[0], fmaf(xv.y, w[1], fmaf(xv.z, w[2], fmaf(xv.w, w[3], acc[r]))));
        }
    }
#pragma unroll
    for (int r = 0; r < 8; ++r) o[(rb + g * 8 + r) * 64 + d] = acc[r];

    if (m == 0) {
        // q0[rb+row] = s0 + xhat_row . vq0 ; row = t>>3, 8-lane segments
        const int row = t >> 3, seg = t & 7;
        float part = 0.f;
#pragma unroll
        for (int kk = 0; kk < 8; ++kk)
            part = fmaf(xs[row * 64 + seg * 8 + kk], vq0s[seg * 8 + kk], part);
        part += __shfl_xor(part, 1);
        part += __shfl_xor(part, 2);
        part += __shfl_xor(part, 4);
        if (seg == 0) q0[rb + row] = part + s0p[0];
    }
}

// ---------- fused edge stream + edge-to-node (512 thr): e_new, Ai (LDS), x_new ----------
__global__ __launch_bounds__(512) void edgenode_kernel(
    const float* __restrict__ e, const float* __restrict__ P,
    const float* __restrict__ q0, const float* __restrict__ Vn,
    const float* __restrict__ Qn, const float* __restrict__ VnWke,
    const float* __restrict__ VnWve, const float* __restrict__ bve,
    float* __restrict__ e_new, float* __restrict__ x_new)
{
    const int bi = blockIdx.x;       // b*512 + i
    const int b = bi >> 9, i = bi & 511;
    const int t = threadIdx.x;

    __shared__ float qn[64], pis[64], vis[64];
    __shared__ float us[512], q0s[512], as_[512], cs[512];
    __shared__ float red[512];

    if (t < 64) {
        qn[t]  = Qn[bi * 64 + t];
        pis[t] = P[bi * 64 + t];
        vis[t] = Vn[bi * 64 + t];
    }
    q0s[t] = q0[b * NN + t];
    __syncthreads();

    // prolog: us[j] = 0.125 * qn . VnWke[b,j]  (4-lane groups, 4 passes)
    {
        const int j4 = t >> 2, l = t & 3;
        const float4* qq = (const float4*)qn;
#pragma unroll
        for (int pass = 0; pass < 4; ++pass) {
            const int j = pass * 128 + j4;
            const float4* wr = (const float4*)(VnWke + (size_t)(b * NN + j) * 64) + l * 4;
            float s = 0.f;
#pragma unroll
            for (int kk = 0; kk < 4; ++kk) {
                const float4 w = wr[kk];
                const float4 qv = qq[l * 4 + kk];
                s += qv.x * w.x + qv.y * w.y + qv.z * w.z + qv.w * w.w;
            }
            s += __shfl_xor(s, 1);
            s += __shfl_xor(s, 2);
            if (l == 0) us[j] = s * 0.125f;
        }
    }

    // phase 1: stream e -> e_new (16 iters, 32 j's per iter)
    const int r = t >> 4;            // j row within chunk (0..31)
    const int k = t & 15;            // float4 lane within row
    const float q0i = q0s[i];
    const float4 pi4 = ((const float4*)pis)[k];
    const float4 vi4 = ((const float4*)vis)[k];
    const f4* erow  = (const f4*)(e     + (size_t)bi * NN * 64);
    f4*       enrow = (f4*)      (e_new + (size_t)bi * NN * 64);

    for (int c0 = 0; c0 < 16; ++c0) {
        const int j  = c0 * 32 + r;
        const int bj = b * NN + j;
        const f4 ev = erow[j * 16 + k];                       // cached load (L3-resident)
        const float4 pj = ((const float4*)P)[bj * 16 + k];
        float s = ev.x * (pj.x - pi4.x) + ev.y * (pj.y - pi4.y)
                + ev.z * (pj.z - pi4.z) + ev.w * (pj.w - pi4.w);
        s += __shfl_xor(s, 1);
        s += __shfl_xor(s, 2);
        s += __shfl_xor(s, 4);
        s += __shfl_xor(s, 8);
        const float ai = 1.f / (1.f + expf(-(s * 0.125f + q0s[j] - q0i)));
        const float4 vj = ((const float4*)Vn)[bj * 16 + k];
        f4 en;
        en.x = fmaf(ai, vj.x - vi4.x, vi4.x);
        en.y = fmaf(ai, vj.y - vi4.y, vi4.y);
        en.z = fmaf(ai, vj.z - vi4.z, vi4.z);
        en.w = fmaf(ai, vj.w - vi4.w, vi4.w);
        __builtin_nontemporal_store(en, enrow + j * 16 + k);
        if (k == 0) as_[j] = ai;
    }
    __syncthreads();

    // phase 2: row softmax over v_j = Ai_j*(u_j - u_i), then PV (512 threads)
    const int lane = t & 63, w = t >> 6;
    const float uii = us[i];
    const float v0 = as_[t] * (us[t] - uii);
    float m = v0;
#pragma unroll
    for (int o = 1; o < 64; o <<= 1) m = fmaxf(m, __shfl_xor(m, o));
    if (lane == 0) red[w] = m;
    __syncthreads();
    float mx = red[0];
#pragma unroll
    for (int z = 1; z < 8; ++z) mx = fmaxf(mx, red[z]);
    const float e0 = expf(v0 - mx);
    float ss = e0;
#pragma unroll
    for (int o = 1; o < 64; o <<= 1) ss += __shfl_xor(ss, o);
    if (lane == 0) red[8 + w] = ss;
    __syncthreads();
    const float inv = 1.f / (red[8] + red[9] + red[10] + red[11]
                           + red[12] + red[13] + red[14] + red[15]);
    const float c0v = e0 * inv * as_[t];
    cs[t] = c0v;
    float gg = c0v;
#pragma unroll
    for (int o = 1; o < 64; o <<= 1) gg += __shfl_xor(gg, o);
    if (lane == 0) red[16 + w] = gg;
    __syncthreads();
    const float g = red[16] + red[17] + red[18] + red[19]
                  + red[20] + red[21] + red[22] + red[23];
    __syncthreads();                     // protect red[] before PV reuse

    const int d = t & 63, q = t >> 6;
    float acc = 0.f;
    const int j0 = q * 64;
    for (int j = j0; j < j0 + 64; ++j)
        acc = fmaf(cs[j], VnWve[(b * NN + j) * 64 + d], acc);
    red[t] = acc;
    __syncthreads();
    if (t < 64) {
        float s8 = 0.f;
#pragma unroll
        for (int z = 0; z < 8; ++z) s8 += red[t + z * 64];
        x_new[bi * 64 + t] = bve[t] + VnWve[bi * 64 + t] * (1.f - g) + s8;
    }
}

extern "C" void kernel_launch(void* const* d_in, const int* in_sizes, int n_in,
                              void* d_out, int out_size, void* d_ws, size_t ws_size,
                              hipStream_t stream) {
    const float* x   = (const float*)d_in[0];
    const float* e   = (const float*)d_in[1];
    const float* Wq1 = (const float*)d_in[2];  const float* bq1 = (const float*)d_in[3];
    const float* Wk1 = (const float*)d_in[4];  const float* bk1 = (const float*)d_in[5];
    const float* Wv1 = (const float*)d_in[6];  const float* bv1 = (const float*)d_in[7];
    const float* Wqe = (const float*)d_in[8];  const float* bqe = (const float*)d_in[9];
    const float* Wkn = (const float*)d_in[10]; const float* bkn = (const float*)d_in[11];
    const float* Wvn = (const float*)d_in[12]; const float* bvn = (const float*)d_in[13];
    const float* Wqn = (const float*)d_in[14]; const float* bqn = (const float*)d_in[15];
    const float* Wke = (const float*)d_in[16]; /* bke cancels in softmax */
    const float* Wve = (const float*)d_in[18]; const float* bve = (const float*)d_in[19];

    float* out = (float*)d_out;
    float* x_new = out;                 // (2,512,64)
    float* e_new = out + 2 * NN * 64;   // (2,512,512,64)

    float* ws = (float*)d_ws;
    const int R = 2 * NN;               // 1024 rows of 64
    float* Q     = ws;                  // R*64 each
    float* K     = Q + R * 64;
    float* V     = K + R * 64;
    float* xhat  = V + R * 64;
    float* Qn    = xhat + R * 64;
    float* Vn    = Qn + R * 64;
    float* P     = Vn + R * 64;
    float* VnWke = P + R * 64;
    float* VnWve = VnWke + R * 64;
    float* q0    = VnWve + R * 64;      // R
    float* M_P   = q0 + R;              // 4096 each
    float* M_ke  = M_P + 4096;
    float* M_ve  = M_ke + 4096;
    float* c_P   = M_ve + 4096;         // 64 each
    float* c_ke  = c_P + 64;
    float* c_ve  = c_ke + 64;
    float* vq0   = c_ve + 64;
    float* s0    = vq0 + 64;            // 1

    precompute_kernel<<<3, 256, 0, stream>>>(Wkn, bkn, Wvn, bvn, Wqe, bqe, Wke, Wve,
                                             M_P, c_P, M_ke, c_ke, M_ve, c_ve, vq0, s0);
    proj3_tiled<<<32, 256, 0, stream>>>(x, Wq1, bq1, Wk1, bk1, Wv1, bv1, Q, K, V);
    selfattn_kernel<<<R, 512, 0, stream>>>(Q, K, V, xhat);
    affine5_kernel<<<dim3(32, 5), 256, 0, stream>>>(xhat, Wqn, bqn, Wvn, bvn,
                                                    M_P, c_P, M_ke, c_ke, M_ve, c_ve,
                                                    vq0, s0,
                                                    Qn, Vn, P, VnWke, VnWve, q0);
    edgenode_kernel<<<R, 512, 0, stream>>>(e, P, q0, Vn, Qn, VnWke, VnWve, bve,
                                           e_new, x_new);
}